// Round 6
// baseline (259.993 us; speedup 1.0000x reference)
//
#include <hip/hip_runtime.h>
#include <math.h>

// out[b,c,n] = softmax_n(max_c x[b,c,n]) * x[b,c,n]   (x: [256,64,2048] fp32)
//
// R8: read-path-cap model. Reads (HBM OR L3) cap at ~3.15 TB/s on this box
// (copy ubench 6.29 = 3.15R+3.15W; write-only fills 6.7; all our read phases
// ~2.9-3.0 regardless of pattern; R0 pass2 = pure L3-reread+write took 45us
// = 128MiB/2.9). So kernel time ~= read-path bytes / 3.15, and all designs
// so far read x TWICE (256 MiB -> ~81us floor, measured 91-98).
// This version reads x ONCE: one 1024-thread block per row holds the row
// on-chip across the softmax — per half-row thread: 16 channels in regs
// (64 VGPR), 3 in LDS (48 KB block total), 13 re-read from L3 in the write
// phase (52 MiB chip-wide, hidden under the 19us HBM write stream).
// Read-path bytes: 256 -> 128 MiB serial + 52 MiB overlapped => ~63-70us
// kernel vs 91-98.

#define B_DIM 256
#define C_DIM 64
#define N_DIM 2048
#define COLS4 (N_DIM / 4)          // 512 float4 columns per row
#define ROW4  (C_DIM * COLS4)      // 32768 float4 per batch row

#define REGS_CH 16                 // channels held in registers (per half)
#define LDS_CH  3                  // channels held in LDS (per half)
#define RR_CH   13                 // channels re-read from L3 (per half)

__global__ __launch_bounds__(1024, 4)
void ssa_gate_fused(const float* __restrict__ x, float* __restrict__ out) {
    const int b    = blockIdx.x;
    const int t    = threadIdx.x;
    const int col  = t & (COLS4 - 1);   // 0..511
    const int grp  = t >> 9;            // half-row: 0 -> ch 0..31, 1 -> ch 32..63
    const int lane = t & 63;
    const int wid  = t >> 6;            // 0..15
    const int c0   = grp * 32;

    const float4* __restrict__ xb = (const float4*)x + (size_t)b * ROW4;
    float4* __restrict__ ob = (float4*)out + (size_t)b * ROW4;

    __shared__ float4 ldsx[2][LDS_CH][COLS4];   // 48 KB: LDS-held channels
    __shared__ float4 xmbuf[COLS4];             // 8 KB: xm partial, then gate
    __shared__ float  sredM[16];
    __shared__ float  sredS[16];

    // ---- Phase 1: read all 32 channels of this half once ----
    float4 r[REGS_CH];
    float4 m = make_float4(-INFINITY, -INFINITY, -INFINITY, -INFINITY);
    #pragma unroll
    for (int c = 0; c < REGS_CH; ++c) {
        r[c] = xb[(size_t)(c0 + c) * COLS4 + col];
        m.x = fmaxf(m.x, r[c].x); m.y = fmaxf(m.y, r[c].y);
        m.z = fmaxf(m.z, r[c].z); m.w = fmaxf(m.w, r[c].w);
    }
    #pragma unroll
    for (int k = 0; k < LDS_CH; ++k) {
        float4 v = xb[(size_t)(c0 + REGS_CH + k) * COLS4 + col];
        ldsx[grp][k][col] = v;
        m.x = fmaxf(m.x, v.x); m.y = fmaxf(m.y, v.y);
        m.z = fmaxf(m.z, v.z); m.w = fmaxf(m.w, v.w);
    }
    #pragma unroll
    for (int k = 0; k < RR_CH; ++k) {
        float4 v = xb[(size_t)(c0 + REGS_CH + LDS_CH + k) * COLS4 + col];
        m.x = fmaxf(m.x, v.x); m.y = fmaxf(m.y, v.y);
        m.z = fmaxf(m.z, v.z); m.w = fmaxf(m.w, v.w);
    }

    // ---- Combine halves: xm per column, then block softmax ----
    if (grp == 1) xmbuf[col] = m;
    __syncthreads();

    float4 e;
    float tm = -INFINITY;
    if (grp == 0) {
        float4 o = xmbuf[col];
        e.x = fmaxf(m.x, o.x); e.y = fmaxf(m.y, o.y);
        e.z = fmaxf(m.z, o.z); e.w = fmaxf(m.w, o.w);
        tm = fmaxf(fmaxf(e.x, e.y), fmaxf(e.z, e.w));
    }
    #pragma unroll
    for (int off = 32; off > 0; off >>= 1)
        tm = fmaxf(tm, __shfl_down(tm, off, 64));
    if (lane == 0) sredM[wid] = tm;             // grp1 waves write -inf: harmless
    __syncthreads();
    float M = sredM[0];
    #pragma unroll
    for (int i = 1; i < 16; ++i) M = fmaxf(M, sredM[i]);

    float ts = 0.0f;
    if (grp == 0) {
        e.x = __expf(e.x - M); e.y = __expf(e.y - M);
        e.z = __expf(e.z - M); e.w = __expf(e.w - M);
        ts = (e.x + e.y) + (e.z + e.w);
    }
    #pragma unroll
    for (int off = 32; off > 0; off >>= 1)
        ts += __shfl_down(ts, off, 64);
    if (lane == 0) sredS[wid] = ts;             // grp1 waves contribute 0
    __syncthreads();
    float S = 0.0f;
    #pragma unroll
    for (int i = 0; i < 16; ++i) S += sredS[i];

    if (grp == 0) {
        const float inv = 1.0f / S;
        float4 g;
        g.x = e.x * inv; g.y = e.y * inv; g.z = e.z * inv; g.w = e.w * inv;
        xmbuf[col] = g;                         // overwrite partial with gate
    }
    __syncthreads();
    const float4 g = xmbuf[col];

    // ---- Phase 2: write all 32 channels; only RR_CH come back via L3 ----
    #pragma unroll
    for (int c = 0; c < REGS_CH; ++c) {
        float4 w;
        w.x = r[c].x * g.x; w.y = r[c].y * g.y;
        w.z = r[c].z * g.z; w.w = r[c].w * g.w;
        ob[(size_t)(c0 + c) * COLS4 + col] = w;
    }
    #pragma unroll
    for (int k = 0; k < LDS_CH; ++k) {
        float4 v = ldsx[grp][k][col];
        float4 w;
        w.x = v.x * g.x; w.y = v.y * g.y;
        w.z = v.z * g.z; w.w = v.w * g.w;
        ob[(size_t)(c0 + REGS_CH + k) * COLS4 + col] = w;
    }
    #pragma unroll
    for (int k = 0; k < RR_CH; ++k) {
        float4 v = xb[(size_t)(c0 + REGS_CH + LDS_CH + k) * COLS4 + col];
        float4 w;
        w.x = v.x * g.x; w.y = v.y * g.y;
        w.z = v.z * g.z; w.w = v.w * g.w;
        ob[(size_t)(c0 + REGS_CH + LDS_CH + k) * COLS4 + col] = w;
    }
}

extern "C" void kernel_launch(void* const* d_in, const int* in_sizes, int n_in,
                              void* d_out, int out_size, void* d_ws, size_t ws_size,
                              hipStream_t stream) {
    const float* x = (const float*)d_in[0];
    float* out = (float*)d_out;
    ssa_gate_fused<<<B_DIM, 1024, 0, stream>>>(x, out);
}